// Round 7
// baseline (4403.297 us; speedup 1.0000x reference)
//
#include <hip/hip_runtime.h>
#include <hip/hip_bf16.h>
#include <cstdint>

#define D_DIM 2048
#define F_DIM 1024
#define E_NUM 64
#define K_TOP 8
#define CAP   1024

typedef __attribute__((ext_vector_type(8))) short short8;
typedef __attribute__((ext_vector_type(4))) float f32x4;

__device__ __forceinline__ uint16_t f_to_bf16(float f) {
    union { float f; uint32_t u; } v; v.f = f;
    uint32_t r = v.u + 0x7FFF + ((v.u >> 16) & 1);
    return (uint16_t)(r >> 16);
}
__device__ __forceinline__ uint32_t pack2(float a, float b) {
    __hip_bfloat162 t = __float22bfloat162_rn(make_float2(a, b));
    return *reinterpret_cast<uint32_t*>(&t);
}
__device__ __forceinline__ short8 pack_frag(const float* v) {
    union { short8 s; uint32_t u[4]; } r;
    r.u[0] = pack2(v[0], v[1]); r.u[1] = pack2(v[2], v[3]);
    r.u[2] = pack2(v[4], v[5]); r.u[3] = pack2(v[6], v[7]);
    return r.s;
}

// ---------------- x -> bf16 ----------------
__global__ __launch_bounds__(256) void cvtx_k(const float* __restrict__ x,
        uint16_t* __restrict__ xb, int n8) {
    int i = blockIdx.x * 256 + threadIdx.x;
    if (i >= n8) return;
    const float4* p = (const float4*)x + (size_t)i * 2;
    float4 a = p[0], b = p[1];
    uint4 o;
    o.x = pack2(a.x, a.y); o.y = pack2(a.z, a.w);
    o.z = pack2(b.x, b.y); o.w = pack2(b.z, b.w);
    ((uint4*)xb)[i] = o;
}

// ---------------- Router ----------------
__global__ __launch_bounds__(64) void router_k(const float* __restrict__ x,
        const float* __restrict__ gw, int* __restrict__ topi,
        float* __restrict__ topw) {
    int t = blockIdx.x;
    int tid = threadIdx.x;
    __shared__ float xs[D_DIM];
    __shared__ float lgs[E_NUM];
    const float* xr = x + (size_t)t * D_DIM;
    for (int d = tid; d < D_DIM; d += 64) xs[d] = xr[d];
    __syncthreads();
    const float* w = gw + (size_t)tid * D_DIM;
    float acc = 0.f;
    #pragma unroll 8
    for (int d = 0; d < D_DIM; ++d) acc = fmaf(xs[d], w[d], acc);
    lgs[tid] = acc;
    __syncthreads();
    if (tid == 0) {
        float mx = -INFINITY;
        for (int e = 0; e < E_NUM; ++e) mx = fmaxf(mx, lgs[e]);
        float se = 0.f;
        for (int e = 0; e < E_NUM; ++e) se += expf(lgs[e] - mx);
        float inv = 1.f / se;
        uint64_t used = 0;
        for (int k = 0; k < K_TOP; ++k) {
            int bi = 0; float bv = -INFINITY;
            for (int e = 0; e < E_NUM; ++e) {
                if (!((used >> e) & 1) && lgs[e] > bv) { bv = lgs[e]; bi = e; }
            }
            used |= 1ull << bi;
            topi[t * K_TOP + k] = bi;
            topw[t * K_TOP + k] = expf(bv - mx) * inv;
        }
    }
}

// ---------------- Slot assignment ----------------
__global__ void assign_k(const int* __restrict__ topi, const float* __restrict__ topw,
        int* __restrict__ cnt, int* __restrict__ rowtok, float* __restrict__ aw, int T) {
    int t = blockIdx.x * blockDim.x + threadIdx.x;
    if (t >= T) return;
    for (int k = 0; k < K_TOP; ++k) {
        int e = topi[t * K_TOP + k];
        int pos = atomicAdd(&cnt[e], 1);
        if (pos < CAP) {
            rowtok[e * CAP + pos] = t;
            aw[e * CAP + pos] = topw[t * K_TOP + k];
        }
    }
}

// ======== Gate+Up: wave-owned 64m x 16f tile, NO LDS, NO BARRIERS ========
// A frags gathered direct from xb (bf16, L2/L3-served); B frags loaded as
// 8 strided fp32 dwords straight from wg/wu, cvt_pk'd in-register.
#define GU_LOAD(A_, BG_, BU_, T_) do {                                        \
    _Pragma("unroll")                                                         \
    for (int mi = 0; mi < 4; ++mi)                                            \
        A_[mi] = *(const uint4*)(agp[mi] + (T_) * 32);                        \
    _Pragma("unroll")                                                         \
    for (int j = 0; j < 8; ++j) {                                             \
        BG_[j] = gp[(size_t)((T_) * 32 + j) * F_DIM];                         \
        BU_[j] = up[(size_t)((T_) * 32 + j) * F_DIM];                         \
    }                                                                         \
} while (0)

#define GU_COMP(A_, BG_, BU_) do {                                            \
    short8 bgf = pack_frag(BG_);                                              \
    short8 buf_ = pack_frag(BU_);                                             \
    _Pragma("unroll")                                                         \
    for (int mi = 0; mi < 4; ++mi) {                                          \
        short8 af = *(const short8*)&A_[mi];                                  \
        accg[mi] = __builtin_amdgcn_mfma_f32_16x16x32_bf16(af, bgf,  accg[mi], 0, 0, 0); \
        accu[mi] = __builtin_amdgcn_mfma_f32_16x16x32_bf16(af, buf_, accu[mi], 0, 0, 0); \
    }                                                                         \
} while (0)

__global__ __launch_bounds__(256) void gateup_k(const uint16_t* __restrict__ xb,
        const float* __restrict__ wg, const float* __restrict__ wu,
        const int* __restrict__ cnt, const int* __restrict__ rowtok,
        uint16_t* __restrict__ h) {
    int b = blockIdx.x;
    int xcd = b & 7;
    int wi = b >> 3;
    int e = xcd * 8 + (wi >> 8);      // each XCD owns 8 experts
    int r = wi & 255;
    int f = r >> 2;                   // 64 f-strips of 16
    int mq = r & 3;
    int tid = threadIdx.x;
    int l = tid & 63, wid = tid >> 6;
    int mtile = mq * 4 + wid;         // 16 m-tiles of 64 rows
    int m0 = mtile * 64;
    int ne = min(cnt[e], CAP);
    int nr = ne - m0;
    if (nr <= 0) return;              // wave-level exit (no barriers -> safe)
    if (nr > 64) nr = 64;
    int slot0e = e * CAP;
    int fbase = f * 16;
    int ln = l & 15, lq = l >> 4;
    int loct = lq * 8;

    const uint16_t* agp[4];
    #pragma unroll
    for (int mi = 0; mi < 4; ++mi) {
        int row = m0 + mi * 16 + ln;
        int tok = rowtok[slot0e + min(row, ne - 1)];
        agp[mi] = xb + (size_t)tok * D_DIM + loct;
    }
    size_t wboff = (size_t)e * ((size_t)D_DIM * F_DIM) + (size_t)loct * F_DIM
                 + (size_t)(fbase + ln);
    const float* gp = wg + wboff;
    const float* up = wu + wboff;

    f32x4 accg[4], accu[4];
    #pragma unroll
    for (int mi = 0; mi < 4; ++mi) {
        accg[mi] = (f32x4){0.f, 0.f, 0.f, 0.f};
        accu[mi] = (f32x4){0.f, 0.f, 0.f, 0.f};
    }

    uint4 aP[4], aQ[4];
    float bgP[8], buP[8], bgQ[8], buQ[8];

    const int NT = D_DIM / 32;        // 64
    GU_LOAD(aP, bgP, buP, 0);
    GU_LOAD(aQ, bgQ, buQ, 1);
    for (int t = 0; t < NT - 2; t += 2) {
        GU_COMP(aP, bgP, buP);
        GU_LOAD(aP, bgP, buP, t + 2);
        GU_COMP(aQ, bgQ, buQ);
        if (t + 3 < NT) GU_LOAD(aQ, bgQ, buQ, t + 3);
    }
    GU_COMP(aP, bgP, buP);
    GU_COMP(aQ, bgQ, buQ);

    #pragma unroll
    for (int mi = 0; mi < 4; ++mi) {
        #pragma unroll
        for (int j = 0; j < 4; ++j) {
            int row = mi * 16 + lq * 4 + j;
            if (row < nr) {
                float g = accg[mi][j], u = accu[mi][j];
                float hv = g / (1.f + __expf(-g)) * u;
                h[(size_t)(slot0e + m0 + row) * F_DIM + fbase + ln] = f_to_bf16(hv);
            }
        }
    }
}

// ======== Down: wave-owned 64m x 32d tile, NO LDS, NO BARRIERS ========
#define DN_LOAD(A_, B0_, B1_, T_) do {                                        \
    _Pragma("unroll")                                                         \
    for (int mi = 0; mi < 4; ++mi)                                            \
        A_[mi] = *(const uint4*)(agp[mi] + (T_) * 32);                        \
    _Pragma("unroll")                                                         \
    for (int j = 0; j < 8; ++j) {                                             \
        B0_[j] = bp[(size_t)((T_) * 32 + j) * D_DIM];                         \
        B1_[j] = bp[(size_t)((T_) * 32 + j) * D_DIM + 16];                    \
    }                                                                         \
} while (0)

#define DN_COMP(A_, B0_, B1_) do {                                            \
    short8 bf0 = pack_frag(B0_);                                              \
    short8 bf1 = pack_frag(B1_);                                              \
    _Pragma("unroll")                                                         \
    for (int mi = 0; mi < 4; ++mi) {                                          \
        short8 af = *(const short8*)&A_[mi];                                  \
        acc0[mi] = __builtin_amdgcn_mfma_f32_16x16x32_bf16(af, bf0, acc0[mi], 0, 0, 0); \
        acc1[mi] = __builtin_amdgcn_mfma_f32_16x16x32_bf16(af, bf1, acc1[mi], 0, 0, 0); \
    }                                                                         \
} while (0)

__global__ __launch_bounds__(256) void down_k(const uint16_t* __restrict__ h,
        const float* __restrict__ wd, const int* __restrict__ cnt,
        const int* __restrict__ rowtok, const float* __restrict__ aw,
        float* __restrict__ out) {
    int b = blockIdx.x;
    int xcd = b & 7;
    int wi = b >> 3;
    int e = xcd * 8 + (wi >> 8);
    int r = wi & 255;
    int dstrip = r >> 2;              // 64 d-strips of 32
    int mq = r & 3;
    int tid = threadIdx.x;
    int l = tid & 63, wid = tid >> 6;
    int mtile = mq * 4 + wid;
    int m0 = mtile * 64;
    int ne = min(cnt[e], CAP);
    int nr = ne - m0;
    if (nr <= 0) return;
    if (nr > 64) nr = 64;
    int slot0e = e * CAP;
    int dbase = dstrip * 32;
    int ln = l & 15, lq = l >> 4;
    int loct = lq * 8;

    const uint16_t* agp[4];
    #pragma unroll
    for (int mi = 0; mi < 4; ++mi)
        agp[mi] = h + (size_t)(slot0e + m0 + mi * 16 + ln) * F_DIM + loct;
    const float* bp = wd + (size_t)e * ((size_t)F_DIM * D_DIM) + (size_t)loct * D_DIM
                    + (size_t)(dbase + ln);

    f32x4 acc0[4], acc1[4];
    #pragma unroll
    for (int mi = 0; mi < 4; ++mi) {
        acc0[mi] = (f32x4){0.f, 0.f, 0.f, 0.f};
        acc1[mi] = (f32x4){0.f, 0.f, 0.f, 0.f};
    }

    uint4 aP[4], aQ[4];
    float b0P[8], b1P[8], b0Q[8], b1Q[8];

    const int NT = F_DIM / 32;        // 32
    DN_LOAD(aP, b0P, b1P, 0);
    DN_LOAD(aQ, b0Q, b1Q, 1);
    for (int t = 0; t < NT - 2; t += 2) {
        DN_COMP(aP, b0P, b1P);
        DN_LOAD(aP, b0P, b1P, t + 2);
        DN_COMP(aQ, b0Q, b1Q);
        if (t + 3 < NT) DN_LOAD(aQ, b0Q, b1Q, t + 3);
    }
    DN_COMP(aP, b0P, b1P);
    DN_COMP(aQ, b0Q, b1Q);

    #pragma unroll
    for (int mi = 0; mi < 4; ++mi) {
        #pragma unroll
        for (int j = 0; j < 4; ++j) {
            int row = mi * 16 + lq * 4 + j;
            if (row < nr) {
                int slot = slot0e + m0 + row;
                int tok = rowtok[slot];
                float wgt = aw[slot];
                float* orow = out + (size_t)tok * D_DIM + dbase + ln;
                atomicAdd(&orow[0],  acc0[mi][j] * wgt);
                atomicAdd(&orow[16], acc1[mi][j] * wgt);
            }
        }
    }
}

extern "C" void kernel_launch(void* const* d_in, const int* in_sizes, int n_in,
                              void* d_out, int out_size, void* d_ws, size_t ws_size,
                              hipStream_t stream) {
    const float* x  = (const float*)d_in[0];
    const float* gw = (const float*)d_in[1];
    const float* wg = (const float*)d_in[2];
    const float* wu = (const float*)d_in[3];
    const float* wd = (const float*)d_in[4];
    float* out = (float*)d_out;
    int T = in_sizes[0] / D_DIM;

    char* ws = (char*)d_ws;
    size_t off = 0;
    auto alloc = [&](size_t bytes) -> void* {
        void* p = ws + off;
        off = (off + bytes + 255) & ~(size_t)255;
        return p;
    };
    int*      cnt    = (int*)     alloc(E_NUM * sizeof(int));
    int*      topi   = (int*)     alloc((size_t)T * K_TOP * sizeof(int));
    float*    topw   = (float*)   alloc((size_t)T * K_TOP * sizeof(float));
    int*      rowtok = (int*)     alloc((size_t)E_NUM * CAP * sizeof(int));
    float*    aw     = (float*)   alloc((size_t)E_NUM * CAP * sizeof(float));
    uint16_t* xb     = (uint16_t*)alloc((size_t)T * D_DIM * sizeof(uint16_t));
    uint16_t* h      = (uint16_t*)alloc((size_t)E_NUM * CAP * F_DIM * sizeof(uint16_t));

    hipMemsetAsync(cnt, 0, E_NUM * sizeof(int), stream);
    hipMemsetAsync(out, 0, (size_t)out_size * sizeof(float), stream);

    int n8 = T * D_DIM / 8;
    cvtx_k<<<(n8 + 255) / 256, 256, 0, stream>>>(x, xb, n8);
    router_k<<<T, 64, 0, stream>>>(x, gw, topi, topw);
    assign_k<<<(T + 255) / 256, 256, 0, stream>>>(topi, topw, cnt, rowtok, aw, T);
    gateup_k<<<E_NUM * 64 * 4, 256, 0, stream>>>(xb, wg, wu, cnt, rowtok, h);
    down_k<<<E_NUM * 64 * 4, 256, 0, stream>>>(h, wd, cnt, rowtok, aw, out);
}

// Round 9
// 1574.473 us; speedup vs baseline: 2.7967x; 2.7967x over previous
//
#include <hip/hip_runtime.h>
#include <hip/hip_bf16.h>
#include <cstdint>

#define D_DIM 2048
#define F_DIM 1024
#define E_NUM 64
#define K_TOP 8
#define CAP   1024

typedef __attribute__((ext_vector_type(8))) short short8;
typedef __attribute__((ext_vector_type(4))) float f32x4;

__device__ __forceinline__ uint16_t f_to_bf16(float f) {
    union { float f; uint32_t u; } v; v.f = f;
    uint32_t r = v.u + 0x7FFF + ((v.u >> 16) & 1);
    return (uint16_t)(r >> 16);
}
__device__ __forceinline__ uint32_t pack2(float a, float b) {
    __hip_bfloat162 t = __float22bfloat162_rn(make_float2(a, b));
    return *reinterpret_cast<uint32_t*>(&t);
}
__device__ __forceinline__ void gload16(const void* g, void* l) {
    __builtin_amdgcn_global_load_lds(
        (const __attribute__((address_space(1))) uint32_t*)g,
        (__attribute__((address_space(3))) uint32_t*)l, 16, 0, 0);
}

// ---------------- x -> bf16 ----------------
__global__ __launch_bounds__(256) void cvtx_k(const float* __restrict__ x,
        uint16_t* __restrict__ xb, int n8) {
    int i = blockIdx.x * 256 + threadIdx.x;
    if (i >= n8) return;
    const float4* p = (const float4*)x + (size_t)i * 2;
    float4 a = p[0], b = p[1];
    uint4 o;
    o.x = pack2(a.x, a.y); o.y = pack2(a.z, a.w);
    o.z = pack2(b.x, b.y); o.w = pack2(b.z, b.w);
    ((uint4*)xb)[i] = o;
}

// ------- weight convert + transpose: src [E][R][C] f32 -> dst [E][C][R] bf16 -------
__global__ __launch_bounds__(256) void cvtw_k(const float* __restrict__ src,
        uint16_t* __restrict__ dst, int R, int C) {
    int e = blockIdx.z;
    int c0 = blockIdx.x * 64;
    int r0 = blockIdx.y * 64;
    __shared__ float ls[64][68];
    int t = threadIdx.x;
    int sr = t >> 2, sc = (t & 3) * 16;
    const float* sp = src + (size_t)e * R * C + (size_t)(r0 + sr) * C + c0 + sc;
    #pragma unroll
    for (int j = 0; j < 4; ++j) {
        float4 v = *(const float4*)(sp + j * 4);
        *(float4*)&ls[sr][sc + j * 4] = v;
    }
    __syncthreads();
    int oc = t >> 2, orr = (t & 3) * 16;
    uint16_t* dp = dst + (size_t)e * C * R + (size_t)(c0 + oc) * R + r0 + orr;
    uint4 o[2];
    uint32_t* ow = (uint32_t*)o;
    #pragma unroll
    for (int j = 0; j < 8; ++j)
        ow[j] = pack2(ls[orr + 2 * j][oc], ls[orr + 2 * j + 1][oc]);
    *(uint4*)(dp) = o[0];
    *(uint4*)(dp + 8) = o[1];
}

// ---------------- Router ----------------
__global__ __launch_bounds__(64) void router_k(const float* __restrict__ x,
        const float* __restrict__ gw, int* __restrict__ topi,
        float* __restrict__ topw) {
    int t = blockIdx.x;
    int tid = threadIdx.x;
    __shared__ float xs[D_DIM];
    __shared__ float lgs[E_NUM];
    const float* xr = x + (size_t)t * D_DIM;
    for (int d = tid; d < D_DIM; d += 64) xs[d] = xr[d];
    __syncthreads();
    const float* w = gw + (size_t)tid * D_DIM;
    float acc = 0.f;
    #pragma unroll 8
    for (int d = 0; d < D_DIM; ++d) acc = fmaf(xs[d], w[d], acc);
    lgs[tid] = acc;
    __syncthreads();
    if (tid == 0) {
        float mx = -INFINITY;
        for (int e = 0; e < E_NUM; ++e) mx = fmaxf(mx, lgs[e]);
        float se = 0.f;
        for (int e = 0; e < E_NUM; ++e) se += expf(lgs[e] - mx);
        float inv = 1.f / se;
        uint64_t used = 0;
        for (int k = 0; k < K_TOP; ++k) {
            int bi = 0; float bv = -INFINITY;
            for (int e = 0; e < E_NUM; ++e) {
                if (!((used >> e) & 1) && lgs[e] > bv) { bv = lgs[e]; bi = e; }
            }
            used |= 1ull << bi;
            topi[t * K_TOP + k] = bi;
            topw[t * K_TOP + k] = expf(bv - mx) * inv;
        }
    }
}

// ---------------- Slot assignment ----------------
__global__ void assign_k(const int* __restrict__ topi, const float* __restrict__ topw,
        int* __restrict__ cnt, int* __restrict__ rowtok, float* __restrict__ aw, int T) {
    int t = blockIdx.x * blockDim.x + threadIdx.x;
    if (t >= T) return;
    for (int k = 0; k < K_TOP; ++k) {
        int e = topi[t * K_TOP + k];
        int pos = atomicAdd(&cnt[e], 1);
        if (pos < CAP) {
            rowtok[e * CAP + pos] = t;
            aw[e * CAP + pos] = topw[t * K_TOP + k];
        }
    }
}

// ======== Gate+Up: 128m x 64f, BK=64, global_load_lds + XOR swizzle ========
// 256 thr, 4 waves 2m x 2f (wave 64m x 32f). LDS 32KB single-buffered.
__global__ __launch_bounds__(256) void gateup_k(const uint16_t* __restrict__ xb,
        const uint16_t* __restrict__ wgt, const uint16_t* __restrict__ wut,
        const int* __restrict__ cnt, const int* __restrict__ rowtok,
        uint16_t* __restrict__ h) {
    int flat = blockIdx.x;
    int xcd = flat & 7;
    int idx = flat >> 3;
    int m = idx & 7;                  // 8 m-tiles -> full CAP=1024 coverage
    int sloc = idx >> 3;              // 0..127
    int strip = sloc * 8 + xcd;       // 0..1023 = e*16 + f  (1024%8==0, bijective)
    int e = strip >> 4;
    int f = strip & 15;
    int m0 = m * 128;
    int ne = min(cnt[e], CAP);
    int nr = ne - m0;
    if (nr <= 0) return;
    if (nr > 128) nr = 128;
    int slot0 = e * CAP + m0;
    int fbase = f * 64;

    __shared__ __align__(16) uint16_t As[128 * 64];   // 16KB, rows 128B
    __shared__ __align__(16) uint16_t Bg[64 * 64];    // 8KB
    __shared__ __align__(16) uint16_t Bu[64 * 64];    // 8KB

    int tid = threadIdx.x;
    int l = tid & 63, wid = tid >> 6;
    int ln = l & 15, lq = l >> 4;
    int wr = wid >> 1, wc = wid & 1;

    // staging pointers (inverse-swizzled global source; LDS dest linear)
    const uint16_t* agp[4];
    #pragma unroll
    for (int i = 0; i < 4; ++i) {
        int c = i * 256 + tid;
        int row = c >> 3, col = c & 7;
        int tok = rowtok[slot0 + min(row, nr - 1)];
        agp[i] = xb + (size_t)tok * D_DIM + ((col ^ (row & 7)) * 8);
    }
    const uint16_t *bgp[2], *bup[2];
    #pragma unroll
    for (int i = 0; i < 2; ++i) {
        int c = i * 256 + tid;
        int row = c >> 3, col = c & 7;
        size_t go = ((size_t)e * F_DIM + fbase + row) * D_DIM + ((col ^ (row & 7)) * 8);
        bgp[i] = wgt + go;
        bup[i] = wut + go;
    }

    f32x4 accg[4][2], accu[4][2];
    #pragma unroll
    for (int mi = 0; mi < 4; ++mi)
        #pragma unroll
        for (int ni = 0; ni < 2; ++ni) {
            accg[mi][ni] = (f32x4){0.f, 0.f, 0.f, 0.f};
            accu[mi][ni] = (f32x4){0.f, 0.f, 0.f, 0.f};
        }

    const int NT = D_DIM / 64;        // 32
    for (int t = 0; t < NT; ++t) {
        int k0 = t * 64;
        #pragma unroll
        for (int i = 0; i < 4; ++i)
            gload16(agp[i] + k0, (char*)As + (i * 256 + wid * 64) * 16);
        #pragma unroll
        for (int i = 0; i < 2; ++i) {
            gload16(bgp[i] + k0, (char*)Bg + (i * 256 + wid * 64) * 16);
            gload16(bup[i] + k0, (char*)Bu + (i * 256 + wid * 64) * 16);
        }
        __syncthreads();
        #pragma unroll
        for (int kk = 0; kk < 2; ++kk) {
            short8 af[4], bg[2], bu[2];
            #pragma unroll
            for (int mi = 0; mi < 4; ++mi) {
                int row = wr * 64 + mi * 16 + ln;
                af[mi] = *(const short8*)((char*)As + row * 128 + (((kk * 4 + lq) ^ (row & 7)) * 16));
            }
            #pragma unroll
            for (int ni = 0; ni < 2; ++ni) {
                int row = wc * 32 + ni * 16 + ln;
                int off = row * 128 + (((kk * 4 + lq) ^ (row & 7)) * 16);
                bg[ni] = *(const short8*)((char*)Bg + off);
                bu[ni] = *(const short8*)((char*)Bu + off);
            }
            #pragma unroll
            for (int mi = 0; mi < 4; ++mi)
                #pragma unroll
                for (int ni = 0; ni < 2; ++ni) {
                    accg[mi][ni] = __builtin_amdgcn_mfma_f32_16x16x32_bf16(af[mi], bg[ni], accg[mi][ni], 0, 0, 0);
                    accu[mi][ni] = __builtin_amdgcn_mfma_f32_16x16x32_bf16(af[mi], bu[ni], accu[mi][ni], 0, 0, 0);
                }
        }
        __syncthreads();
    }

    #pragma unroll
    for (int mi = 0; mi < 4; ++mi) {
        #pragma unroll
        for (int j = 0; j < 4; ++j) {
            int row = wr * 64 + mi * 16 + lq * 4 + j;
            if (row < nr) {
                size_t hb = (size_t)(slot0 + row) * F_DIM + fbase + wc * 32 + ln;
                #pragma unroll
                for (int ni = 0; ni < 2; ++ni) {
                    float g = accg[mi][ni][j], u = accu[mi][ni][j];
                    h[hb + ni * 16] = f_to_bf16(g / (1.f + __expf(-g)) * u);
                }
            }
        }
    }
}

// ======== Down: 128m x 64d, BK=64, global_load_lds + XOR swizzle ========
__global__ __launch_bounds__(256) void down_k(const uint16_t* __restrict__ h,
        const uint16_t* __restrict__ wdt, const int* __restrict__ cnt,
        const int* __restrict__ rowtok, const float* __restrict__ aw,
        float* __restrict__ out) {
    int flat = blockIdx.x;
    int xcd = flat & 7;
    int idx = flat >> 3;
    int m = idx & 7;                  // 8 m-tiles -> full CAP coverage
    int sloc = idx >> 3;              // 0..255
    int strip = sloc * 8 + xcd;       // 0..2047 = e*32 + dt (2048%8==0, bijective)
    int e = strip >> 5;
    int dt = strip & 31;
    int m0 = m * 128;
    int ne = min(cnt[e], CAP);
    int nr = ne - m0;
    if (nr <= 0) return;
    if (nr > 128) nr = 128;
    int slot0 = e * CAP + m0;
    int dbase = dt * 64;

    __shared__ __align__(16) uint16_t As[128 * 64];
    __shared__ __align__(16) uint16_t Bs[64 * 64];

    int tid = threadIdx.x;
    int l = tid & 63, wid = tid >> 6;
    int ln = l & 15, lq = l >> 4;
    int wr = wid >> 1, wc = wid & 1;

    const uint16_t* agp[4];
    #pragma unroll
    for (int i = 0; i < 4; ++i) {
        int c = i * 256 + tid;
        int row = c >> 3, col = c & 7;
        agp[i] = h + (size_t)(slot0 + min(row, nr - 1)) * F_DIM + ((col ^ (row & 7)) * 8);
    }
    const uint16_t* bp[2];
    #pragma unroll
    for (int i = 0; i < 2; ++i) {
        int c = i * 256 + tid;
        int row = c >> 3, col = c & 7;
        bp[i] = wdt + ((size_t)e * D_DIM + dbase + row) * F_DIM + ((col ^ (row & 7)) * 8);
    }

    f32x4 acc[4][2];
    #pragma unroll
    for (int mi = 0; mi < 4; ++mi)
        #pragma unroll
        for (int ni = 0; ni < 2; ++ni)
            acc[mi][ni] = (f32x4){0.f, 0.f, 0.f, 0.f};

    const int NT = F_DIM / 64;        // 16
    for (int t = 0; t < NT; ++t) {
        int k0 = t * 64;
        #pragma unroll
        for (int i = 0; i < 4; ++i)
            gload16(agp[i] + k0, (char*)As + (i * 256 + wid * 64) * 16);
        #pragma unroll
        for (int i = 0; i < 2; ++i)
            gload16(bp[i] + k0, (char*)Bs + (i * 256 + wid * 64) * 16);
        __syncthreads();
        #pragma unroll
        for (int kk = 0; kk < 2; ++kk) {
            short8 af[4], bf[2];
            #pragma unroll
            for (int mi = 0; mi < 4; ++mi) {
                int row = wr * 64 + mi * 16 + ln;
                af[mi] = *(const short8*)((char*)As + row * 128 + (((kk * 4 + lq) ^ (row & 7)) * 16));
            }
            #pragma unroll
            for (int ni = 0; ni < 2; ++ni) {
                int row = wc * 32 + ni * 16 + ln;
                bf[ni] = *(const short8*)((char*)Bs + row * 128 + (((kk * 4 + lq) ^ (row & 7)) * 16));
            }
            #pragma unroll
            for (int mi = 0; mi < 4; ++mi)
                #pragma unroll
                for (int ni = 0; ni < 2; ++ni)
                    acc[mi][ni] = __builtin_amdgcn_mfma_f32_16x16x32_bf16(af[mi], bf[ni], acc[mi][ni], 0, 0, 0);
        }
        __syncthreads();
    }

    #pragma unroll
    for (int mi = 0; mi < 4; ++mi) {
        #pragma unroll
        for (int j = 0; j < 4; ++j) {
            int row = wr * 64 + mi * 16 + lq * 4 + j;
            if (row < nr) {
                int slot = slot0 + row;
                int tok = rowtok[slot];
                float wgt = aw[slot];
                float* orow = out + (size_t)tok * D_DIM + dbase + wc * 32 + ln;
                #pragma unroll
                for (int ni = 0; ni < 2; ++ni)
                    atomicAdd(&orow[ni * 16], acc[mi][ni][j] * wgt);
            }
        }
    }
}

extern "C" void kernel_launch(void* const* d_in, const int* in_sizes, int n_in,
                              void* d_out, int out_size, void* d_ws, size_t ws_size,
                              hipStream_t stream) {
    const float* x  = (const float*)d_in[0];
    const float* gw = (const float*)d_in[1];
    const float* wg = (const float*)d_in[2];
    const float* wu = (const float*)d_in[3];
    const float* wd = (const float*)d_in[4];
    float* out = (float*)d_out;
    int T = in_sizes[0] / D_DIM;

    char* ws = (char*)d_ws;
    size_t off = 0;
    auto alloc = [&](size_t bytes) -> void* {
        void* p = ws + off;
        off = (off + bytes + 255) & ~(size_t)255;
        return p;
    };
    int*      cnt    = (int*)     alloc(E_NUM * sizeof(int));
    int*      topi   = (int*)     alloc((size_t)T * K_TOP * sizeof(int));
    float*    topw   = (float*)   alloc((size_t)T * K_TOP * sizeof(float));
    int*      rowtok = (int*)     alloc((size_t)E_NUM * CAP * sizeof(int));
    float*    aw     = (float*)   alloc((size_t)E_NUM * CAP * sizeof(float));
    uint16_t* xb     = (uint16_t*)alloc((size_t)T * D_DIM * sizeof(uint16_t));
    uint16_t* h      = (uint16_t*)alloc((size_t)E_NUM * CAP * F_DIM * sizeof(uint16_t));
    uint16_t* wgt    = (uint16_t*)alloc((size_t)E_NUM * D_DIM * F_DIM * sizeof(uint16_t));
    uint16_t* wut    = (uint16_t*)alloc((size_t)E_NUM * D_DIM * F_DIM * sizeof(uint16_t));
    uint16_t* wdt    = wgt;   // alias: gateup finishes before wd conversion (stream-ordered)

    hipMemsetAsync(cnt, 0, E_NUM * sizeof(int), stream);
    hipMemsetAsync(out, 0, (size_t)out_size * sizeof(float), stream);

    int n8 = T * D_DIM / 8;
    cvtx_k<<<(n8 + 255) / 256, 256, 0, stream>>>(x, xb, n8);
    router_k<<<T, 64, 0, stream>>>(x, gw, topi, topw);
    assign_k<<<(T + 255) / 256, 256, 0, stream>>>(topi, topw, cnt, rowtok, aw, T);
    // convert+transpose gate/up weights: [E][D][F] f32 -> [E][F][D] bf16
    cvtw_k<<<dim3(F_DIM / 64, D_DIM / 64, E_NUM), 256, 0, stream>>>(wg, wgt, D_DIM, F_DIM);
    cvtw_k<<<dim3(F_DIM / 64, D_DIM / 64, E_NUM), 256, 0, stream>>>(wu, wut, D_DIM, F_DIM);
    gateup_k<<<E_NUM * 16 * 8, 256, 0, stream>>>(xb, wgt, wut, cnt, rowtok, h);
    // convert+transpose down weights: [E][F][D] f32 -> [E][D][F] bf16 (aliases wgt)
    cvtw_k<<<dim3(D_DIM / 64, F_DIM / 64, E_NUM), 256, 0, stream>>>(wd, wdt, F_DIM, D_DIM);
    down_k<<<E_NUM * 32 * 8, 256, 0, stream>>>(h, wdt, cnt, rowtok, aw, out);
}